// Round 12
// baseline (21.403 us; speedup 1.0000x reference)
//
#include <hip/hip_runtime.h>

#define WIRES 14
#define NVB 13                // variational blocks

__device__ __forceinline__ float2 cmul(float2 a, float2 b) {
    return make_float2(a.x * b.x - a.y * b.y, a.x * b.y + a.y * b.x);
}

// Fuse one 10-gate variational block k into a single complex 4x4 (local basis:
// b1 = q1 = first qubit of the pair). Verbatim math from the verified pipeline.
__device__ void fuse_block(const float* __restrict__ p, float2* __restrict__ Gk) {
    float2 U1[4], U2[4], U3[4], U4[4];
    auto rzrx = [](float trx, float trz, float2* U) {
        float cx, sx, cz, sz;
        sincosf(trx * 0.5f, &sx, &cx);
        sincosf(trz * 0.5f, &sz, &cz);
        float2 e0 = make_float2(cz, -sz);   // e^{-i h}
        float2 e1 = make_float2(cz,  sz);   // e^{+i h}
        U[0] = cmul(e0, make_float2(cx, 0.f));
        U[1] = cmul(e0, make_float2(0.f, -sx));
        U[2] = cmul(e1, make_float2(0.f, -sx));
        U[3] = cmul(e1, make_float2(cx, 0.f));
    };
    rzrx(p[0], p[1], U1);   // q1, first
    rzrx(p[2], p[3], U2);   // q2, first
    rzrx(p[5], p[6], U3);   // q1, second
    rzrx(p[7], p[8], U4);   // q2, second

    float2 K12[16], K34[16];
    #pragma unroll
    for (int r1 = 0; r1 < 2; ++r1)
        #pragma unroll
        for (int r2 = 0; r2 < 2; ++r2)
            #pragma unroll
            for (int c1 = 0; c1 < 2; ++c1)
                #pragma unroll
                for (int c2 = 0; c2 < 2; ++c2) {
                    int idx = (r1 * 2 + r2) * 4 + (c1 * 2 + c2);
                    K12[idx] = cmul(U1[r1 * 2 + c1], U2[r2 * 2 + c2]);
                    K34[idx] = cmul(U3[r1 * 2 + c1], U4[r2 * 2 + c2]);
                }

    float2 C1[16], C2[16];
    #pragma unroll
    for (int i = 0; i < 16; ++i) { C1[i] = make_float2(0.f, 0.f); C2[i] = make_float2(0.f, 0.f); }
    {
        float c, s;
        sincosf(p[4] * 0.5f, &s, &c);        // CRY ctrl=q1(high local bit), tgt=q2
        C1[0]  = make_float2(1.f, 0.f); C1[5]  = make_float2(1.f, 0.f);
        C1[10] = make_float2(c, 0.f);   C1[11] = make_float2(-s, 0.f);
        C1[14] = make_float2(s, 0.f);   C1[15] = make_float2(c, 0.f);
        sincosf(p[9] * 0.5f, &s, &c);        // CRY ctrl=q2(low local bit), tgt=q1
        C2[0]  = make_float2(1.f, 0.f); C2[10] = make_float2(1.f, 0.f);
        C2[5]  = make_float2(c, 0.f);   C2[7]  = make_float2(-s, 0.f);
        C2[13] = make_float2(s, 0.f);   C2[15] = make_float2(c, 0.f);
    }

    float2 T1[16], T2[16];
    #pragma unroll
    for (int r = 0; r < 4; ++r)
        #pragma unroll
        for (int c = 0; c < 4; ++c) {
            float2 a = make_float2(0.f, 0.f);
            #pragma unroll
            for (int j = 0; j < 4; ++j) { float2 m = cmul(C1[r*4+j], K12[j*4+c]); a.x += m.x; a.y += m.y; }
            T1[r*4+c] = a;
        }
    #pragma unroll
    for (int r = 0; r < 4; ++r)
        #pragma unroll
        for (int c = 0; c < 4; ++c) {
            float2 a = make_float2(0.f, 0.f);
            #pragma unroll
            for (int j = 0; j < 4; ++j) { float2 m = cmul(K34[r*4+j], T1[j*4+c]); a.x += m.x; a.y += m.y; }
            T2[r*4+c] = a;
        }
    #pragma unroll
    for (int r = 0; r < 4; ++r)
        #pragma unroll
        for (int c = 0; c < 4; ++c) {
            float2 a = make_float2(0.f, 0.f);
            #pragma unroll
            for (int j = 0; j < 4; ++j) { float2 m = cmul(C2[r*4+j], T2[j*4+c]); a.x += m.x; a.y += m.y; }
            Gk[r*4+c] = a;
        }
}

// ============ single kernel: one thread = one sample (all 14 outputs) ============
// Light-cone identity (depth-2 brick wall): with u[s] = G[s]·(RY(inp[2s])⊗RY(inp[2s+1]))|00>,
// seg s (a=2s+1) needs only v1=u[s], v2=u[s+1], W=G[7+s]; Z_0 from u[0]; Z_13 from u[6].
// Lanes 0..12 fuse the 13 blocks into LDS once per block; each thread then
// computes u[0..6] (7 ryblks, 14 sincosf) and all 14 expectation values.
__global__ __launch_bounds__(256)
void lightcone_fused(const float* __restrict__ inputs, const float* __restrict__ params,
                     float* __restrict__ out, int batch) {
    __shared__ float2 Gs[NVB * 16];
    const int t = threadIdx.x;
    if (t < NVB) fuse_block(params + t * 10, Gs + t * 16);
    __syncthreads();

    const int b = blockIdx.x * 256 + t;
    if (b >= batch) return;
    const float* inp = inputs + b * WIRES;

    // u[s] = G[s] * (RY ⊗ RY)|00>, basis j = (q_{2s} << 1) | q_{2s+1}
    float2 u[7][4];
    #pragma unroll
    for (int s = 0; s < 7; ++s) {
        float cp, sp, cq, sq;
        sincosf(inp[2*s]     * 0.5f, &sp, &cp);
        sincosf(inp[2*s + 1] * 0.5f, &sq, &cq);
        const float e0 = cp * cq, e1 = cp * sq, e2 = sp * cq, e3 = sp * sq;
        const float2* B = Gs + s * 16;
        #pragma unroll
        for (int j = 0; j < 4; ++j) {
            u[s][j].x = B[j*4+0].x*e0 + B[j*4+1].x*e1 + B[j*4+2].x*e2 + B[j*4+3].x*e3;
            u[s][j].y = B[j*4+0].y*e0 + B[j*4+1].y*e1 + B[j*4+2].y*e2 + B[j*4+3].y*e3;
        }
    }

    float z[WIRES];

    // Z_0 from u[0] (bit1 of index = qubit 0); Z_13 from u[6] (bit0 = qubit 13)
    {
        float p0 = u[0][0].x*u[0][0].x + u[0][0].y*u[0][0].y;
        float p1 = u[0][1].x*u[0][1].x + u[0][1].y*u[0][1].y;
        float p2 = u[0][2].x*u[0][2].x + u[0][2].y*u[0][2].y;
        float p3 = u[0][3].x*u[0][3].x + u[0][3].y*u[0][3].y;
        z[0] = (p0 + p1) - (p2 + p3);
        p0 = u[6][0].x*u[6][0].x + u[6][0].y*u[6][0].y;
        p1 = u[6][1].x*u[6][1].x + u[6][1].y*u[6][1].y;
        p2 = u[6][2].x*u[6][2].x + u[6][2].y*u[6][2].y;
        p3 = u[6][3].x*u[6][3].x + u[6][3].y*u[6][3].y;
        z[13] = (p0 - p1) + (p2 - p3);
    }

    // segs 0..5: a = 2s+1; 4-bit index (b3,b2,b1,b0) = (q_{a-1}, q_a, q_{a+1}, q_{a+2})
    #pragma unroll
    for (int s = 0; s < 6; ++s) {
        const float2* v1 = u[s];
        const float2* v2 = u[s + 1];
        const float2* W = Gs + (7 + s) * 16;      // L2 on (a, a+1), bit1 = a
        float za = 0.f, zb = 0.f;
        #pragma unroll
        for (int b3 = 0; b3 < 2; ++b3)
            #pragma unroll
            for (int b0 = 0; b0 < 2; ++b0) {
                float2 x[4], y[4];
                #pragma unroll
                for (int j = 0; j < 4; ++j)
                    x[j] = cmul(v1[(b3 << 1) | (j >> 1)], v2[((j & 1) << 1) | b0]);
                #pragma unroll
                for (int j = 0; j < 4; ++j) {
                    float2 acc = make_float2(0.f, 0.f);
                    #pragma unroll
                    for (int k = 0; k < 4; ++k) {
                        float2 m = cmul(W[j*4+k], x[k]);
                        acc.x += m.x; acc.y += m.y;
                    }
                    y[j] = acc;
                }
                #pragma unroll
                for (int j = 0; j < 4; ++j) {
                    float p = y[j].x * y[j].x + y[j].y * y[j].y;
                    za += (j & 2) ? -p : p;    // bit2 = qubit a
                    zb += (j & 1) ? -p : p;    // bit1 = qubit a+1
                }
            }
        z[2*s + 1] = za;
        z[2*s + 2] = zb;
    }

    #pragma unroll
    for (int q = 0; q < WIRES; ++q) out[b * WIRES + q] = z[q];
}

extern "C" void kernel_launch(void* const* d_in, const int* in_sizes, int n_in,
                              void* d_out, int out_size, void* d_ws, size_t ws_size,
                              hipStream_t stream) {
    const float* inputs = (const float*)d_in[0];
    const float* params = (const float*)d_in[1];
    float* out = (float*)d_out;

    const int batch = in_sizes[0] / WIRES;
    lightcone_fused<<<(batch + 255) / 256, 256, 0, stream>>>(inputs, params, out, batch);
}

// Round 13
// 11.851 us; speedup vs baseline: 1.8060x; 1.8060x over previous
//
#include <hip/hip_runtime.h>

#define WIRES 14
#define NVB 13                // variational blocks
#define BLK 64                // one wave per block -> 128 blocks, more CUs engaged

__device__ __forceinline__ float2 cmul(float2 a, float2 b) {
    return make_float2(a.x * b.x - a.y * b.y, a.x * b.y + a.y * b.x);
}

// Fuse one 10-gate variational block k into a single complex 4x4 (local basis:
// b1 = q1 = first qubit of the pair). Verbatim math from the verified pipeline.
__device__ void fuse_block(const float* __restrict__ p, float2* __restrict__ Gk) {
    float2 U1[4], U2[4], U3[4], U4[4];
    auto rzrx = [](float trx, float trz, float2* U) {
        float cx, sx, cz, sz;
        sincosf(trx * 0.5f, &sx, &cx);
        sincosf(trz * 0.5f, &sz, &cz);
        float2 e0 = make_float2(cz, -sz);   // e^{-i h}
        float2 e1 = make_float2(cz,  sz);   // e^{+i h}
        U[0] = cmul(e0, make_float2(cx, 0.f));
        U[1] = cmul(e0, make_float2(0.f, -sx));
        U[2] = cmul(e1, make_float2(0.f, -sx));
        U[3] = cmul(e1, make_float2(cx, 0.f));
    };
    rzrx(p[0], p[1], U1);   // q1, first
    rzrx(p[2], p[3], U2);   // q2, first
    rzrx(p[5], p[6], U3);   // q1, second
    rzrx(p[7], p[8], U4);   // q2, second

    float2 K12[16], K34[16];
    #pragma unroll
    for (int r1 = 0; r1 < 2; ++r1)
        #pragma unroll
        for (int r2 = 0; r2 < 2; ++r2)
            #pragma unroll
            for (int c1 = 0; c1 < 2; ++c1)
                #pragma unroll
                for (int c2 = 0; c2 < 2; ++c2) {
                    int idx = (r1 * 2 + r2) * 4 + (c1 * 2 + c2);
                    K12[idx] = cmul(U1[r1 * 2 + c1], U2[r2 * 2 + c2]);
                    K34[idx] = cmul(U3[r1 * 2 + c1], U4[r2 * 2 + c2]);
                }

    float2 C1[16], C2[16];
    #pragma unroll
    for (int i = 0; i < 16; ++i) { C1[i] = make_float2(0.f, 0.f); C2[i] = make_float2(0.f, 0.f); }
    {
        float c, s;
        sincosf(p[4] * 0.5f, &s, &c);        // CRY ctrl=q1(high local bit), tgt=q2
        C1[0]  = make_float2(1.f, 0.f); C1[5]  = make_float2(1.f, 0.f);
        C1[10] = make_float2(c, 0.f);   C1[11] = make_float2(-s, 0.f);
        C1[14] = make_float2(s, 0.f);   C1[15] = make_float2(c, 0.f);
        sincosf(p[9] * 0.5f, &s, &c);        // CRY ctrl=q2(low local bit), tgt=q1
        C2[0]  = make_float2(1.f, 0.f); C2[10] = make_float2(1.f, 0.f);
        C2[5]  = make_float2(c, 0.f);   C2[7]  = make_float2(-s, 0.f);
        C2[13] = make_float2(s, 0.f);   C2[15] = make_float2(c, 0.f);
    }

    float2 T1[16], T2[16];
    #pragma unroll
    for (int r = 0; r < 4; ++r)
        #pragma unroll
        for (int c = 0; c < 4; ++c) {
            float2 a = make_float2(0.f, 0.f);
            #pragma unroll
            for (int j = 0; j < 4; ++j) { float2 m = cmul(C1[r*4+j], K12[j*4+c]); a.x += m.x; a.y += m.y; }
            T1[r*4+c] = a;
        }
    #pragma unroll
    for (int r = 0; r < 4; ++r)
        #pragma unroll
        for (int c = 0; c < 4; ++c) {
            float2 a = make_float2(0.f, 0.f);
            #pragma unroll
            for (int j = 0; j < 4; ++j) { float2 m = cmul(K34[r*4+j], T1[j*4+c]); a.x += m.x; a.y += m.y; }
            T2[r*4+c] = a;
        }
    #pragma unroll
    for (int r = 0; r < 4; ++r)
        #pragma unroll
        for (int c = 0; c < 4; ++c) {
            float2 a = make_float2(0.f, 0.f);
            #pragma unroll
            for (int j = 0; j < 4; ++j) { float2 m = cmul(C2[r*4+j], T2[j*4+c]); a.x += m.x; a.y += m.y; }
            Gk[r*4+c] = a;
        }
}

// ============ single fused kernel: per-block gate fusion + light-cone eval ============
// Depth-2 brick wall => <Z_q> depends on at most 4 qubits:
//   q in layer-2 pair (a,a+1), a=2*seg+1: cone = {a-1,a,a+1,a+2};
//   blocks: L1 G[seg] on (a-1,a), L1 G[seg+1] on (a+1,a+2), L2 G[7+seg] on (a,a+1).
//   seg 6 -> Z_0 via G[0] only; seg 7 -> Z_13 via G[6] only.
// grid = (batch/BLK, 8); seg uniform per block (no divergence); lanes 0..2
// fuse the <=3 needed matrices into LDS.
__global__ __launch_bounds__(BLK)
void lightcone_fused(const float* __restrict__ inputs, const float* __restrict__ params,
                     float* __restrict__ out, int batch) {
    __shared__ float2 Gs[3 * 16];      // [0]=L1 left, [1]=L1 right, [2]=L2
    const int seg = blockIdx.y;
    const int t = threadIdx.x;

    if (seg < 6) {
        if (t < 3) {
            const int k = (t == 0) ? seg : (t == 1) ? (seg + 1) : (7 + seg);
            fuse_block(params + k * 10, Gs + t * 16);
        }
    } else {
        if (t == 0) fuse_block(params + (seg == 6 ? 0 : 6) * 10, Gs);
    }
    __syncthreads();

    const int b = blockIdx.x * BLK + t;
    if (b >= batch) return;
    const float* inp = inputs + b * WIRES;

    // v = B * (RY(tp) (x) RY(tq)) |00>  — B complex 4x4, product state real
    auto ryblk = [](const float2* __restrict__ B, float tp, float tq, float2 v[4]) {
        float cp, sp, cq, sq;
        sincosf(tp * 0.5f, &sp, &cp);
        sincosf(tq * 0.5f, &sq, &cq);
        const float e0 = cp * cq, e1 = cp * sq, e2 = sp * cq, e3 = sp * sq;
        #pragma unroll
        for (int j = 0; j < 4; ++j) {
            v[j].x = B[j*4+0].x*e0 + B[j*4+1].x*e1 + B[j*4+2].x*e2 + B[j*4+3].x*e3;
            v[j].y = B[j*4+0].y*e0 + B[j*4+1].y*e1 + B[j*4+2].y*e2 + B[j*4+3].y*e3;
        }
    };

    if (seg < 6) {
        const int a = 2 * seg + 1;
        float2 v1[4], v2[4];
        ryblk(Gs + 0 * 16, inp[a - 1], inp[a],     v1);   // (a-1, a)
        ryblk(Gs + 1 * 16, inp[a + 1], inp[a + 2], v2);   // (a+1, a+2)
        const float2* W = Gs + 2 * 16;                    // L2 on (a, a+1)

        float za = 0.f, zb = 0.f;
        #pragma unroll
        for (int b3 = 0; b3 < 2; ++b3)
            #pragma unroll
            for (int b0 = 0; b0 < 2; ++b0) {
                // x[j], j=(b2<<1)|b1 : psi = v1[(b3<<1)|b2] * v2[(b1<<1)|b0]
                float2 x[4], y[4];
                #pragma unroll
                for (int j = 0; j < 4; ++j)
                    x[j] = cmul(v1[(b3 << 1) | (j >> 1)], v2[((j & 1) << 1) | b0]);
                #pragma unroll
                for (int j = 0; j < 4; ++j) {
                    float2 acc = make_float2(0.f, 0.f);
                    #pragma unroll
                    for (int k = 0; k < 4; ++k) {
                        float2 m = cmul(W[j*4+k], x[k]);
                        acc.x += m.x; acc.y += m.y;
                    }
                    y[j] = acc;
                }
                #pragma unroll
                for (int j = 0; j < 4; ++j) {
                    float p = y[j].x * y[j].x + y[j].y * y[j].y;
                    za += (j & 2) ? -p : p;    // bit2 = qubit a
                    zb += (j & 1) ? -p : p;    // bit1 = qubit a+1
                }
            }
        out[b * WIRES + a]     = za;
        out[b * WIRES + a + 1] = zb;
    } else if (seg == 6) {
        float2 v[4];
        ryblk(Gs, inp[0], inp[1], v);           // block 0 on (0,1)
        float p0 = v[0].x*v[0].x + v[0].y*v[0].y;
        float p1 = v[1].x*v[1].x + v[1].y*v[1].y;
        float p2 = v[2].x*v[2].x + v[2].y*v[2].y;
        float p3 = v[3].x*v[3].x + v[3].y*v[3].y;
        out[b * WIRES + 0] = (p0 + p1) - (p2 + p3);   // bit1 = qubit 0
    } else {
        float2 v[4];
        ryblk(Gs, inp[12], inp[13], v);         // block 6 on (12,13)
        float p0 = v[0].x*v[0].x + v[0].y*v[0].y;
        float p1 = v[1].x*v[1].x + v[1].y*v[1].y;
        float p2 = v[2].x*v[2].x + v[2].y*v[2].y;
        float p3 = v[3].x*v[3].x + v[3].y*v[3].y;
        out[b * WIRES + 13] = (p0 - p1) + (p2 - p3);  // bit0 = qubit 13
    }
}

extern "C" void kernel_launch(void* const* d_in, const int* in_sizes, int n_in,
                              void* d_out, int out_size, void* d_ws, size_t ws_size,
                              hipStream_t stream) {
    const float* inputs = (const float*)d_in[0];
    const float* params = (const float*)d_in[1];
    float* out = (float*)d_out;

    const int batch = in_sizes[0] / WIRES;
    dim3 grid((batch + BLK - 1) / BLK, 8);
    lightcone_fused<<<grid, BLK, 0, stream>>>(inputs, params, out, batch);
}